// Round 15
// baseline (64.988 us; speedup 1.0000x reference)
//
#include <hip/hip_runtime.h>
#include <hip/hip_bf16.h>
#include <math.h>

// Problem constants
#define N_TOK 196
#define M_KV  23520      // (C/4)*N
#define EPSN  1e-3f
#define LOG2E 1.44269504088896340736f

// Workspace layout (in floats)
#define OFF_QC    0
#define OFF_KC    94080
#define OFF_VC    188160
#define OFF_ATTN  282240   // 480*480 raw attn scores
#define OFF_KV    512640   // float2[4*23520]
#define OFF_SPART 700800   // 225*2 psi1 [sum,sumsq] per-block partials
#define OFF_KPART 701312   // [2 stats][4 heads][128 slots] = 1024 floats

__device__ __forceinline__ float fast_exp2(float x) {
#if __has_builtin(__builtin_amdgcn_exp2f)
    return __builtin_amdgcn_exp2f(x);
#else
    return exp2f(x);
#endif
}

#define GEMM_COMPUTE4(AS, BS) \
    _Pragma("unroll") \
    for (int kk2 = 0; kk2 < 16; ++kk2) { \
        float2 av = *(const float2*)&AS[kk2][ty*2]; \
        float2 bv = *(const float2*)&BS[kk2][tx*2]; \
        a00 = fmaf(av.x, bv.x, a00); a01 = fmaf(av.x, bv.y, a01); \
        a10 = fmaf(av.y, bv.x, a10); a11 = fmaf(av.y, bv.y, a11); \
    }

// ---------------- K1: Qc/Kc/Vc = emb_C @ W  (315 blocks x 512) --------------
// 32x32 tile, grid (15 n, 7 m, 3 mat); 2-way K-split (240+240).
// A[k][m] from embC rows (coalesced along k), B[k][n] from W rows.
__global__ __launch_bounds__(512) void k_qkv(const float* __restrict__ embC,
                                             const float* __restrict__ Wq,
                                             const float* __restrict__ Wk,
                                             const float* __restrict__ Wv,
                                             float* __restrict__ ws) {
    int zi = blockIdx.z;
    int m0 = blockIdx.y * 32, n0 = blockIdx.x * 32;
    const float* W = (zi == 0) ? Wq : (zi == 1 ? Wk : Wv);
    float* o = ws + zi * 94080;
    __shared__ float As[2][2][16][36];
    __shared__ float Bs[2][2][16][36];
    __shared__ float Cmb[32][33];
    int tid = threadIdx.x;
    int kg = tid >> 8, t = tid & 255;
    int ty = t >> 4, tx = t & 15;
    float a00=0,a01=0,a10=0,a11=0;
    const float2 z2 = make_float2(0,0);
    // A stager: row mm (32), k-pair kq2 (16)
    int mm = t >> 3, kq2 = (t & 7) * 2;
    bool am = (m0 + mm) < N_TOK;
    const float* aptr = embC + (m0 + mm) * 480 + kg * 240 + kq2;
    // B stager: k-row kk (16), n-pair eq (32)
    int kk = t >> 4, eq = (t & 15) * 2;
    const float* bptr = W + (kg * 240 + kk) * 480 + n0 + eq;
    const int NS = 15;
    float2 ra = am ? *(const float2*)(aptr) : z2;
    float2 rb = *(const float2*)(bptr);
    As[kg][0][kq2][mm] = ra.x; As[kg][0][kq2+1][mm] = ra.y;
    *(float2*)&Bs[kg][0][kk][eq] = rb;
    ra = am ? *(const float2*)(aptr + 16) : z2;
    rb = *(const float2*)(bptr + 16*480);
    __syncthreads();
    for (int s = 0; s < NS; ++s) {
        int b = s & 1;
        float2 fa = z2, fb = z2;
        if (s + 2 < NS) {
            fa = am ? *(const float2*)(aptr + (s+2)*16) : z2;
            fb = *(const float2*)(bptr + (s+2)*16*480);
        }
        GEMM_COMPUTE4(As[kg][b], Bs[kg][b]);
        if (s + 1 < NS) {
            int nb = b ^ 1;
            As[kg][nb][kq2][mm] = ra.x; As[kg][nb][kq2+1][mm] = ra.y;
            *(float2*)&Bs[kg][nb][kk][eq] = rb;
        }
        __syncthreads();
        ra = fa; rb = fb;
    }
    if (kg == 1) {
        Cmb[ty*2+0][tx*2] = a00; Cmb[ty*2+0][tx*2+1] = a01;
        Cmb[ty*2+1][tx*2] = a10; Cmb[ty*2+1][tx*2+1] = a11;
    }
    __syncthreads();
    if (kg == 0) {
        a00 += Cmb[ty*2+0][tx*2]; a01 += Cmb[ty*2+0][tx*2+1];
        a10 += Cmb[ty*2+1][tx*2]; a11 += Cmb[ty*2+1][tx*2+1];
        int m = m0 + ty*2, n = n0 + tx*2;
        if (m   < N_TOK) *(float2*)(o + (m  )*480 + n) = make_float2(a00, a01);
        if (m+1 < N_TOK) *(float2*)(o + (m+1)*480 + n) = make_float2(a10, a11);
    }
}

// ---------------- K2: attn = Qc^T @ Kc + psi1 partials (225 blocks x 512) ---
__global__ __launch_bounds__(512) void k_attn(const float* __restrict__ Qc,
                                              const float* __restrict__ Kc,
                                              float* __restrict__ attn,
                                              float* __restrict__ Spart) {
    __shared__ float As[2][2][16][36];
    __shared__ float Bs[2][2][16][36];
    __shared__ float Cmb[32][33];
    __shared__ float red[8][2];
    int tid = threadIdx.x;
    int kg = tid >> 8, t = tid & 255;
    int n0 = blockIdx.x * 32, m0 = blockIdx.y * 32;
    int ty = t >> 4, tx = t & 15;
    float a00=0,a01=0,a10=0,a11=0;
    const float2 z2 = make_float2(0,0);
    int kk = t >> 4, eq = (t & 15) * 2;
    int kbase = kg * 112;
    const float* aptr = Qc + kk * 480 + m0 + eq;
    const float* bptr = Kc + kk * 480 + n0 + eq;
    const int NS = 7;
    float2 ra = (kbase + kk < N_TOK) ? *(const float2*)(aptr + kbase*480) : z2;
    float2 rb = (kbase + kk < N_TOK) ? *(const float2*)(bptr + kbase*480) : z2;
    *(float2*)&As[kg][0][kk][eq] = ra;
    *(float2*)&Bs[kg][0][kk][eq] = rb;
    bool v1 = (kbase + 16 + kk) < N_TOK;
    ra = v1 ? *(const float2*)(aptr + (kbase+16)*480) : z2;
    rb = v1 ? *(const float2*)(bptr + (kbase+16)*480) : z2;
    __syncthreads();
    for (int s = 0; s < NS; ++s) {
        int b = s & 1;
        float2 fa = z2, fb = z2;
        if (s + 2 < NS) {
            int k0 = kbase + (s + 2) * 16;
            if (k0 + kk < N_TOK) {
                fa = *(const float2*)(aptr + k0*480);
                fb = *(const float2*)(bptr + k0*480);
            }
        }
        GEMM_COMPUTE4(As[kg][b], Bs[kg][b]);
        if (s + 1 < NS) {
            int nb = b ^ 1;
            *(float2*)&As[kg][nb][kk][eq] = ra;
            *(float2*)&Bs[kg][nb][kk][eq] = rb;
        }
        __syncthreads();
        ra = fa; rb = fb;
    }
    if (kg == 1) {
        Cmb[ty*2+0][tx*2] = a00; Cmb[ty*2+0][tx*2+1] = a01;
        Cmb[ty*2+1][tx*2] = a10; Cmb[ty*2+1][tx*2+1] = a11;
    }
    __syncthreads();
    float ls = 0.f, lq = 0.f;
    if (kg == 0) {
        a00 += Cmb[ty*2+0][tx*2]; a01 += Cmb[ty*2+0][tx*2+1];
        a10 += Cmb[ty*2+1][tx*2]; a11 += Cmb[ty*2+1][tx*2+1];
        int m = m0 + ty*2, n = n0 + tx*2;
        *(float2*)(attn + (m  )*480 + n) = make_float2(a00, a01);
        *(float2*)(attn + (m+1)*480 + n) = make_float2(a10, a11);
        ls = a00+a01+a10+a11;
        lq = a00*a00+a01*a01+a10*a10+a11*a11;
    }
    #pragma unroll
    for (int o = 32; o > 0; o >>= 1) { ls += __shfl_xor(ls, o, 64); lq += __shfl_xor(lq, o, 64); }
    int wid = tid >> 6, lane = tid & 63;
    if (lane == 0) { red[wid][0] = ls; red[wid][1] = lq; }
    __syncthreads();
    if (tid == 0) {
        int bid = blockIdx.y * gridDim.x + blockIdx.x;
        float S = 0.f, SQ = 0.f;
        #pragma unroll
        for (int w = 0; w < 8; ++w) { S += red[w][0]; SQ += red[w][1]; }
        Spart[bid*2]   = S;
        Spart[bid*2+1] = SQ;
    }
}

// ------- K3: softmax + T_hat GEMM + KV projection + kpart (105 blocks x 512) -
__global__ __launch_bounds__(512) void k_thatkv(const float* __restrict__ Vc,
                                                const float* __restrict__ attn,
                                                const float* __restrict__ Spart,
                                                const float* __restrict__ g1,
                                                const float* __restrict__ Wk,
                                                const float* __restrict__ Wv,
                                                float2* __restrict__ KV,
                                                float* __restrict__ kpart) {
    __shared__ float As[2][2][16][36];
    __shared__ float Bs[2][2][16][36];
    __shared__ float Cmb[32][33];
    __shared__ float Tile[32][33];
    __shared__ float red[8][8];
    __shared__ float colsum[32];
    int bid = blockIdx.x;
    int n0 = (bid % 15) * 32, m0 = (bid / 15) * 32;
    int tid = threadIdx.x;
    int kg = tid >> 8, t = tid & 255;
    int wid = tid >> 6, lane = tid & 63;
    if (tid < 32) colsum[tid] = 0.f;
    float ps = 0.f, pq = 0.f;
    if (tid < 225) { ps = Spart[tid*2]; pq = Spart[tid*2+1]; }
    #pragma unroll
    for (int o = 32; o > 0; o >>= 1) { ps += __shfl_xor(ps, o, 64); pq += __shfl_xor(pq, o, 64); }
    __shared__ float pr[8][2];
    if (lane == 0) { pr[wid][0] = ps; pr[wid][1] = pq; }
    __syncthreads();
    float S = 0.f, SQ = 0.f;
    #pragma unroll
    for (int w = 0; w < 8; ++w) { S += pr[w][0]; SQ += pr[w][1]; }
    const float invCC = 1.f / (480.f * 480.f);
    float mean = S * invCC;
    float var  = SQ * invCC - mean * mean;
    float s2 = g1[0] * rsqrtf(var + EPSN) * LOG2E;
    int ty = t >> 4, tx = t & 15;
    float a00=0,a01=0,a10=0,a11=0;
    const float2 z2 = make_float2(0,0);
    int mm = t >> 3, kq2 = (t & 7) * 2;
    bool am = (m0 + mm) < N_TOK;
    const float* aptr = Vc + (m0 + mm) * 480 + kg * 240 + kq2;
    const float* bptr = attn + (n0 + mm) * 480 + kg * 240 + kq2;
    float bsum = 0.f;
    const int NS = 15;
    float2 ra = am ? *(const float2*)(aptr) : z2;
    float2 rb = *(const float2*)(bptr);
    As[kg][0][kq2][mm] = ra.x; As[kg][0][kq2+1][mm] = ra.y;
    {
        float e0 = fast_exp2(s2 * rb.x), e1 = fast_exp2(s2 * rb.y);
        Bs[kg][0][kq2][mm] = e0; Bs[kg][0][kq2+1][mm] = e1;
        bsum += e0 + e1;
    }
    ra = am ? *(const float2*)(aptr + 16) : z2;
    rb = *(const float2*)(bptr + 16);
    __syncthreads();
    for (int s = 0; s < NS; ++s) {
        int b = s & 1;
        float2 fa = z2, fb = z2;
        if (s + 2 < NS) {
            fa = am ? *(const float2*)(aptr + (s+2)*16) : z2;
            fb = *(const float2*)(bptr + (s+2)*16);
        }
        GEMM_COMPUTE4(As[kg][b], Bs[kg][b]);
        if (s + 1 < NS) {
            int nb = b ^ 1;
            As[kg][nb][kq2][mm] = ra.x; As[kg][nb][kq2+1][mm] = ra.y;
            float e0 = fast_exp2(s2 * rb.x), e1 = fast_exp2(s2 * rb.y);
            Bs[kg][nb][kq2][mm] = e0; Bs[kg][nb][kq2+1][mm] = e1;
            bsum += e0 + e1;
        }
        __syncthreads();
        ra = fa; rb = fb;
    }
    atomicAdd(&colsum[mm], bsum);
    int r0 = ty*2, cc = tx*2;
    if (kg == 1) {
        Cmb[r0+0][cc] = a00; Cmb[r0+0][cc+1] = a01;
        Cmb[r0+1][cc] = a10; Cmb[r0+1][cc+1] = a11;
    }
    __syncthreads();
    if (tid < 32) colsum[tid] = 1.f / colsum[tid];
    __syncthreads();
    if (kg == 0) {
        float i0 = colsum[cc], i1 = colsum[cc+1];
        Tile[r0+0][cc] = (Cmb[r0+0][cc] + a00) * i0; Tile[r0+0][cc+1] = (Cmb[r0+0][cc+1] + a01) * i1;
        Tile[r0+1][cc] = (Cmb[r0+1][cc] + a10) * i0; Tile[r0+1][cc+1] = (Cmb[r0+1][cc+1] + a11) * i1;
    }
    __syncthreads();
    float su[4] = {0,0,0,0}, sq[4] = {0,0,0,0};
    if (tid < 256) {
        int tr = tid >> 3, jj = tid & 7;
        int tok = m0 + tr;
        bool act = tok < N_TOK;
        float c0 = Tile[tr][4*jj], c1 = Tile[tr][4*jj+1];
        float c2 = Tile[tr][4*jj+2], c3 = Tile[tr][4*jj+3];
        int m_kv = (n0/4 + jj) * 196 + tok;
        #pragma unroll
        for (int h = 0; h < 4; ++h) {
            float kh = c0*Wk[h] + c1*Wk[4+h] + c2*Wk[8+h] + c3*Wk[12+h];
            float vh = c0*Wv[h] + c1*Wv[4+h] + c2*Wv[8+h] + c3*Wv[12+h];
            if (act) {
                KV[h * M_KV + m_kv] = make_float2(kh, vh);
                su[h] += kh; sq[h] += kh * kh;
            }
        }
    }
    __syncthreads();
    #pragma unroll
    for (int h = 0; h < 4; ++h) {
        #pragma unroll
        for (int o = 32; o > 0; o >>= 1) {
            su[h] += __shfl_xor(su[h], o, 64);
            sq[h] += __shfl_xor(sq[h], o, 64);
        }
        if (lane == 0) { red[wid][h*2+0] = su[h]; red[wid][h*2+1] = sq[h]; }
    }
    __syncthreads();
    if (tid < 8) {
        int h = tid & 3, st = tid >> 2;
        float r = 0.f;
        #pragma unroll
        for (int w = 0; w < 8; ++w) r += red[w][h*2+st];
        kpart[st * 512 + h * 128 + bid] = r;
    }
}

// -------- K4: branch attention, full-K per block, in-block finalize ---------
#define QG 49
__global__ __launch_bounds__(1024) void k_branch(
        const float* __restrict__ emb1, const float* __restrict__ emb2,
        const float* __restrict__ emb3, const float* __restrict__ emb4,
        const float* __restrict__ Wq1, const float* __restrict__ Wq2,
        const float* __restrict__ Wq3, const float* __restrict__ Wq4,
        const float* __restrict__ g2v,
        const float2* __restrict__ KV, const float* __restrict__ kpart,
        const float* __restrict__ Wo1, const float* __restrict__ Wo2,
        const float* __restrict__ Wo3, const float* __restrict__ Wo4,
        float* __restrict__ out) {
    __shared__ float lsh[4][4][4];
    __shared__ float ash[4][4][4];
    int tid = threadIdx.x;
    int w = tid >> 6, lane = tid & 63;
    int h = w >> 2, p = w & 3;
    int bid = blockIdx.x;
    int i = bid / QG, qg = bid % QG;
    const float* emb = (i == 0) ? emb1 : (i == 1) ? emb2 : (i == 2) ? emb3 : emb4;
    const float* Wq  = (i == 0) ? Wq1 : (i == 1) ? Wq2 : (i == 2) ? Wq3 : Wq4;
    float wq0 = Wq[h], wq1 = Wq[4+h], wq2 = Wq[8+h], wq3 = Wq[12+h];
    float s = 0.f, s2 = 0.f;
    #pragma unroll
    for (int r = 0; r < 4; ++r) {
        int tt = lane + r * 64;
        if (tt < N_TOK) {
            float Q = emb[tt*4]*wq0 + emb[tt*4+1]*wq1 + emb[tt*4+2]*wq2 + emb[tt*4+3]*wq3;
            s += Q; s2 += Q * Q;
        }
    }
    float ks  = kpart[0*512 + h*128 + lane];
    float kq2 = kpart[1*512 + h*128 + lane];
    if (lane + 64 < 105) {
        ks  += kpart[0*512 + h*128 + 64 + lane];
        kq2 += kpart[1*512 + h*128 + 64 + lane];
    }
    #pragma unroll
    for (int o = 32; o > 0; o >>= 1) {
        s += __shfl_xor(s, o, 64); s2 += __shfl_xor(s2, o, 64);
        ks += __shfl_xor(ks, o, 64); kq2 += __shfl_xor(kq2, o, 64);
    }
    float Qbar = s * (1.f/196.f), Q2bar = s2 * (1.f/196.f);
    float Kbar = ks * (1.f/(float)M_KV), K2bar = kq2 * (1.f/(float)M_KV);
    float mu = Qbar * Kbar;
    float var = Q2bar * K2bar - mu * mu;
    float sc = g2v[h] * rsqrtf(var + EPSN);
    float B2[4];
    #pragma unroll
    for (int j = 0; j < 4; ++j) {
        int q = qg * 4 + j;
        float Qj = emb[q*4]*wq0 + emb[q*4+1]*wq1 + emb[q*4+2]*wq2 + emb[q*4+3]*wq3;
        B2[j] = Qj * sc * LOG2E;
    }
    const float4* kv4 = (const float4*)(KV + h * M_KV);
    const int KQ = M_KV / 8;
    int kstart = p * KQ, kendq = kstart + KQ;
    float l[4] = {0,0,0,0};
    float a[4] = {0,0,0,0};
#define PROC8(P) { \
        _Pragma("unroll") \
        for (int j = 0; j < 4; ++j) { \
            float x = fast_exp2(B2[j] * P.x); \
            l[j] += x; a[j] = fmaf(x, P.y, a[j]); \
            float y = fast_exp2(B2[j] * P.z); \
            l[j] += y; a[j] = fmaf(y, P.w, a[j]); \
        } }
    int k4 = kstart + lane;
    for (; k4 + 192 < kendq; k4 += 256) {
        float4 p0 = kv4[k4], p1 = kv4[k4+64], p2 = kv4[k4+128], p3 = kv4[k4+192];
        PROC8(p0); PROC8(p1); PROC8(p2); PROC8(p3);
    }
    for (; k4 < kendq; k4 += 64) { float4 pv = kv4[k4]; PROC8(pv); }
#undef PROC8
    #pragma unroll
    for (int j = 0; j < 4; ++j) {
        float lv = l[j], av = a[j];
        #pragma unroll
        for (int o = 32; o > 0; o >>= 1) { lv += __shfl_xor(lv, o, 64); av += __shfl_xor(av, o, 64); }
        if (lane == 0) { lsh[h][p][j] = lv; ash[h][p][j] = av; }
    }
    __syncthreads();
    if (tid < 4) {
        const float* Wo = (i == 0) ? Wo1 : (i == 1) ? Wo2 : (i == 2) ? Wo3 : Wo4;
        int j = tid;
        float c[4];
        #pragma unroll
        for (int hh = 0; hh < 4; ++hh) {
            float L = lsh[hh][0][j] + lsh[hh][1][j] + lsh[hh][2][j] + lsh[hh][3][j];
            float A = ash[hh][0][j] + ash[hh][1][j] + ash[hh][2][j] + ash[hh][3][j];
            c[hh] = A / L;
        }
        float4 o;
        o.x = c[0]*Wo[0] + c[1]*Wo[4] + c[2]*Wo[8]  + c[3]*Wo[12];
        o.y = c[0]*Wo[1] + c[1]*Wo[5] + c[2]*Wo[9]  + c[3]*Wo[13];
        o.z = c[0]*Wo[2] + c[1]*Wo[6] + c[2]*Wo[10] + c[3]*Wo[14];
        o.w = c[0]*Wo[3] + c[1]*Wo[7] + c[2]*Wo[11] + c[3]*Wo[15];
        *(float4*)(out + i * 784 + (qg * 4 + j) * 4) = o;
    }
}

extern "C" void kernel_launch(void* const* d_in, const int* in_sizes, int n_in,
                              void* d_out, int out_size, void* d_ws, size_t ws_size,
                              hipStream_t stream) {
    const float* emb1 = (const float*)d_in[0];
    const float* emb2 = (const float*)d_in[1];
    const float* emb3 = (const float*)d_in[2];
    const float* emb4 = (const float*)d_in[3];
    const float* embC = (const float*)d_in[4];
    const float* WqC  = (const float*)d_in[5];
    const float* WkC  = (const float*)d_in[6];
    const float* WvC  = (const float*)d_in[7];
    const float* Wq1  = (const float*)d_in[8];
    const float* Wq2  = (const float*)d_in[9];
    const float* Wq3  = (const float*)d_in[10];
    const float* Wq4  = (const float*)d_in[11];
    const float* Wk   = (const float*)d_in[12];
    const float* Wv   = (const float*)d_in[13];
    const float* Wo1  = (const float*)d_in[14];
    const float* Wo2  = (const float*)d_in[15];
    const float* Wo3  = (const float*)d_in[16];
    const float* Wo4  = (const float*)d_in[17];
    const float* g1   = (const float*)d_in[18];
    const float* g2   = (const float*)d_in[20];
    float* ws = (float*)d_ws;
    float* out = (float*)d_out;

    k_qkv<<<dim3(15, 7, 3), 512, 0, stream>>>(embC, WqC, WkC, WvC, ws);
    k_attn<<<dim3(15, 15), 512, 0, stream>>>(ws + OFF_QC, ws + OFF_KC,
                                             ws + OFF_ATTN, ws + OFF_SPART);
    k_thatkv<<<105, 512, 0, stream>>>(ws + OFF_VC, ws + OFF_ATTN, ws + OFF_SPART, g1,
                                      Wk, Wv, (float2*)(ws + OFF_KV), ws + OFF_KPART);
    k_branch<<<4 * QG, 1024, 0, stream>>>(emb1, emb2, emb3, emb4,
                                          Wq1, Wq2, Wq3, Wq4, g2,
                                          (const float2*)(ws + OFF_KV), ws + OFF_KPART,
                                          Wo1, Wo2, Wo3, Wo4, out);
}

// Round 16
// 62.073 us; speedup vs baseline: 1.0470x; 1.0470x over previous
//
#include <hip/hip_runtime.h>
#include <hip/hip_bf16.h>
#include <math.h>

// Problem constants
#define N_TOK 196
#define M_KV  23520      // (C/4)*N
#define EPSN  1e-3f
#define LOG2E 1.44269504088896340736f

// Workspace layout (in floats)
#define OFF_QC    0
#define OFF_KC    94080
#define OFF_VC    188160
#define OFF_ATTN  282240   // 480*480 raw attn scores
#define OFF_KV    512640   // float2[4*23520]
#define OFF_SPART 700800   // 225*2 psi1 [sum,sumsq] per-block partials
#define OFF_KPART 701312   // [2 stats][4 heads][128 slots] = 1024 floats

__device__ __forceinline__ float fast_exp2(float x) {
#if __has_builtin(__builtin_amdgcn_exp2f)
    return __builtin_amdgcn_exp2f(x);
#else
    return exp2f(x);
#endif
}

#define GEMM_COMPUTE8(AS, BS) \
    _Pragma("unroll") \
    for (int kk2 = 0; kk2 < 16; ++kk2) { \
        float4 av = *(const float4*)&AS[kk2][ty*4]; \
        float2 bv = *(const float2*)&BS[kk2][tx*2]; \
        a00 = fmaf(av.x, bv.x, a00); a01 = fmaf(av.x, bv.y, a01); \
        a10 = fmaf(av.y, bv.x, a10); a11 = fmaf(av.y, bv.y, a11); \
        a20 = fmaf(av.z, bv.x, a20); a21 = fmaf(av.z, bv.y, a21); \
        a30 = fmaf(av.w, bv.x, a30); a31 = fmaf(av.w, bv.y, a31); \
    }

#define GEMM_COMPUTE4(AS, BS) \
    _Pragma("unroll") \
    for (int kk2 = 0; kk2 < 16; ++kk2) { \
        float2 av = *(const float2*)&AS[kk2][ty*2]; \
        float2 bv = *(const float2*)&BS[kk2][tx*2]; \
        a00 = fmaf(av.x, bv.x, a00); a01 = fmaf(av.x, bv.y, a01); \
        a10 = fmaf(av.y, bv.x, a10); a11 = fmaf(av.y, bv.y, a11); \
    }

// ---------------- K1: Qc/Kc/Vc = emb_C @ W  (180 blocks x 512) --------------
// Round-14 config: 64x32 tile, float4 staging, 2-way K-split (240+240).
__global__ __launch_bounds__(512) void k_qkv(const float* __restrict__ embC,
                                             const float* __restrict__ Wq,
                                             const float* __restrict__ Wk,
                                             const float* __restrict__ Wv,
                                             float* __restrict__ ws) {
    int bid = blockIdx.x;
    int zi = bid / 60, rem = bid % 60;
    int m0 = (rem / 15) * 64, n0 = (rem % 15) * 32;
    const float* W = (zi == 0) ? Wq : (zi == 1 ? Wk : Wv);
    float* o = ws + zi * 94080;
    __shared__ float As[2][2][16][68];
    __shared__ float Bs[2][2][16][36];
    __shared__ float Cmb[64][33];
    int tid = threadIdx.x;
    int kg = tid >> 8, t = tid & 255;
    int ty = t >> 4, tx = t & 15;
    float a00=0,a01=0,a10=0,a11=0,a20=0,a21=0,a30=0,a31=0;
    const float4 z4 = make_float4(0,0,0,0);
    int mrow = t >> 2, kq = (t & 3) * 4;
    bool am = (m0 + mrow) < N_TOK;
    const float* aptr = embC + (m0 + mrow) * 480 + kg * 240 + kq;
    bool bact = t < 128;
    int kk = t >> 3, nq = (t & 7) * 4;
    const float* bptr = W + (kg * 240 + kk) * 480 + n0 + nq;
    const int NS = 15;
    float4 ra = am ? *(const float4*)(aptr) : z4;
    float4 rb = bact ? *(const float4*)(bptr) : z4;
    As[kg][0][kq+0][mrow]=ra.x; As[kg][0][kq+1][mrow]=ra.y;
    As[kg][0][kq+2][mrow]=ra.z; As[kg][0][kq+3][mrow]=ra.w;
    if (bact) *(float4*)&Bs[kg][0][kk][nq] = rb;
    ra = am ? *(const float4*)(aptr + 16) : z4;
    rb = bact ? *(const float4*)(bptr + 16*480) : z4;
    __syncthreads();
    for (int s = 0; s < NS; ++s) {
        int b = s & 1;
        float4 fa = z4, fb = z4;
        if (s + 2 < NS) {
            fa = am ? *(const float4*)(aptr + (s+2)*16) : z4;
            fb = bact ? *(const float4*)(bptr + (s+2)*16*480) : z4;
        }
        GEMM_COMPUTE8(As[kg][b], Bs[kg][b]);
        if (s + 1 < NS) {
            int nb = b ^ 1;
            As[kg][nb][kq+0][mrow]=ra.x; As[kg][nb][kq+1][mrow]=ra.y;
            As[kg][nb][kq+2][mrow]=ra.z; As[kg][nb][kq+3][mrow]=ra.w;
            if (bact) *(float4*)&Bs[kg][nb][kk][nq] = rb;
        }
        __syncthreads();
        ra = fa; rb = fb;
    }
    if (kg == 1) {
        Cmb[ty*4+0][tx*2] = a00; Cmb[ty*4+0][tx*2+1] = a01;
        Cmb[ty*4+1][tx*2] = a10; Cmb[ty*4+1][tx*2+1] = a11;
        Cmb[ty*4+2][tx*2] = a20; Cmb[ty*4+2][tx*2+1] = a21;
        Cmb[ty*4+3][tx*2] = a30; Cmb[ty*4+3][tx*2+1] = a31;
    }
    __syncthreads();
    if (kg == 0) {
        a00 += Cmb[ty*4+0][tx*2]; a01 += Cmb[ty*4+0][tx*2+1];
        a10 += Cmb[ty*4+1][tx*2]; a11 += Cmb[ty*4+1][tx*2+1];
        a20 += Cmb[ty*4+2][tx*2]; a21 += Cmb[ty*4+2][tx*2+1];
        a30 += Cmb[ty*4+3][tx*2]; a31 += Cmb[ty*4+3][tx*2+1];
        int m = m0 + ty*4, n = n0 + tx*2;
        if (m   < N_TOK) *(float2*)(o + (m  )*480 + n) = make_float2(a00, a01);
        if (m+1 < N_TOK) *(float2*)(o + (m+1)*480 + n) = make_float2(a10, a11);
        if (m+2 < N_TOK) *(float2*)(o + (m+2)*480 + n) = make_float2(a20, a21);
        if (m+3 < N_TOK) *(float2*)(o + (m+3)*480 + n) = make_float2(a30, a31);
    }
}

// ---------------- K2: attn = Qc^T @ Kc + psi1 partials (225 blocks x 512) ---
// 32x32 tile: grid 15x15 covers 480x480 exactly (no phantom rows -> clean stats).
__global__ __launch_bounds__(512) void k_attn(const float* __restrict__ Qc,
                                              const float* __restrict__ Kc,
                                              float* __restrict__ attn,
                                              float* __restrict__ Spart) {
    __shared__ float As[2][2][16][36];
    __shared__ float Bs[2][2][16][36];
    __shared__ float Cmb[32][33];
    __shared__ float red[8][2];
    int tid = threadIdx.x;
    int kg = tid >> 8, t = tid & 255;
    int n0 = blockIdx.x * 32, m0 = blockIdx.y * 32;
    int ty = t >> 4, tx = t & 15;
    float a00=0,a01=0,a10=0,a11=0;
    const float2 z2 = make_float2(0,0);
    int kk = t >> 4, eq = (t & 15) * 2;
    int kbase = kg * 112;
    const float* aptr = Qc + kk * 480 + m0 + eq;
    const float* bptr = Kc + kk * 480 + n0 + eq;
    const int NS = 7;
    float2 ra = (kbase + kk < N_TOK) ? *(const float2*)(aptr + kbase*480) : z2;
    float2 rb = (kbase + kk < N_TOK) ? *(const float2*)(bptr + kbase*480) : z2;
    *(float2*)&As[kg][0][kk][eq] = ra;
    *(float2*)&Bs[kg][0][kk][eq] = rb;
    bool v1 = (kbase + 16 + kk) < N_TOK;
    ra = v1 ? *(const float2*)(aptr + (kbase+16)*480) : z2;
    rb = v1 ? *(const float2*)(bptr + (kbase+16)*480) : z2;
    __syncthreads();
    for (int s = 0; s < NS; ++s) {
        int b = s & 1;
        float2 fa = z2, fb = z2;
        if (s + 2 < NS) {
            int k0 = kbase + (s + 2) * 16;
            if (k0 + kk < N_TOK) {
                fa = *(const float2*)(aptr + k0*480);
                fb = *(const float2*)(bptr + k0*480);
            }
        }
        GEMM_COMPUTE4(As[kg][b], Bs[kg][b]);
        if (s + 1 < NS) {
            int nb = b ^ 1;
            *(float2*)&As[kg][nb][kk][eq] = ra;
            *(float2*)&Bs[kg][nb][kk][eq] = rb;
        }
        __syncthreads();
        ra = fa; rb = fb;
    }
    if (kg == 1) {
        Cmb[ty*2+0][tx*2] = a00; Cmb[ty*2+0][tx*2+1] = a01;
        Cmb[ty*2+1][tx*2] = a10; Cmb[ty*2+1][tx*2+1] = a11;
    }
    __syncthreads();
    float ls = 0.f, lq = 0.f;
    if (kg == 0) {
        a00 += Cmb[ty*2+0][tx*2]; a01 += Cmb[ty*2+0][tx*2+1];
        a10 += Cmb[ty*2+1][tx*2]; a11 += Cmb[ty*2+1][tx*2+1];
        int m = m0 + ty*2, n = n0 + tx*2;
        *(float2*)(attn + (m  )*480 + n) = make_float2(a00, a01);
        *(float2*)(attn + (m+1)*480 + n) = make_float2(a10, a11);
        ls = a00+a01+a10+a11;
        lq = a00*a00+a01*a01+a10*a10+a11*a11;
    }
    #pragma unroll
    for (int o = 32; o > 0; o >>= 1) { ls += __shfl_xor(ls, o, 64); lq += __shfl_xor(lq, o, 64); }
    int wid = tid >> 6, lane = tid & 63;
    if (lane == 0) { red[wid][0] = ls; red[wid][1] = lq; }
    __syncthreads();
    if (tid == 0) {
        int bid = blockIdx.y * gridDim.x + blockIdx.x;
        float S = 0.f, SQ = 0.f;
        #pragma unroll
        for (int w = 0; w < 8; ++w) { S += red[w][0]; SQ += red[w][1]; }
        Spart[bid*2]   = S;
        Spart[bid*2+1] = SQ;
    }
}

// ------- K3: softmax + T_hat GEMM + KV projection + kpart (105 blocks x 512) -
// 32x32 tile: grid 15(n) x 7(m). Deferred normalization.
__global__ __launch_bounds__(512) void k_thatkv(const float* __restrict__ Vc,
                                                const float* __restrict__ attn,
                                                const float* __restrict__ Spart,
                                                const float* __restrict__ g1,
                                                const float* __restrict__ Wk,
                                                const float* __restrict__ Wv,
                                                float2* __restrict__ KV,
                                                float* __restrict__ kpart) {
    __shared__ float As[2][2][16][36];
    __shared__ float Bs[2][2][16][36];
    __shared__ float Cmb[32][33];
    __shared__ float Tile[32][33];
    __shared__ float red[8][8];
    __shared__ float colsum[32];
    int bid = blockIdx.x;
    int n0 = (bid % 15) * 32, m0 = (bid / 15) * 32;
    int tid = threadIdx.x;
    int kg = tid >> 8, t = tid & 255;
    int wid = tid >> 6, lane = tid & 63;
    if (tid < 32) colsum[tid] = 0.f;
    // ---- psi1 scale from 225 partials ----
    float ps = 0.f, pq = 0.f;
    if (tid < 225) { ps = Spart[tid*2]; pq = Spart[tid*2+1]; }
    #pragma unroll
    for (int o = 32; o > 0; o >>= 1) { ps += __shfl_xor(ps, o, 64); pq += __shfl_xor(pq, o, 64); }
    __shared__ float pr[8][2];
    if (lane == 0) { pr[wid][0] = ps; pr[wid][1] = pq; }
    __syncthreads();
    float S = 0.f, SQ = 0.f;
    #pragma unroll
    for (int w = 0; w < 8; ++w) { S += pr[w][0]; SQ += pr[w][1]; }
    const float invCC = 1.f / (480.f * 480.f);
    float mean = S * invCC;
    float var  = SQ * invCC - mean * mean;
    float s2 = g1[0] * rsqrtf(var + EPSN) * LOG2E;
    // ---- K-split GEMM: A = Vc (tok x d), B = exp2(s2*attn[n][k]) ----
    int ty = t >> 4, tx = t & 15;
    float a00=0,a01=0,a10=0,a11=0;
    const float2 z2 = make_float2(0,0);
    int mm = t >> 3, kq2 = (t & 7) * 2;
    bool am = (m0 + mm) < N_TOK;
    const float* aptr = Vc + (m0 + mm) * 480 + kg * 240 + kq2;
    const float* bptr = attn + (n0 + mm) * 480 + kg * 240 + kq2;
    float bsum = 0.f;
    const int NS = 15;
    float2 ra = am ? *(const float2*)(aptr) : z2;
    float2 rb = *(const float2*)(bptr);
    As[kg][0][kq2][mm] = ra.x; As[kg][0][kq2+1][mm] = ra.y;
    {
        float e0 = fast_exp2(s2 * rb.x), e1 = fast_exp2(s2 * rb.y);
        Bs[kg][0][kq2][mm] = e0; Bs[kg][0][kq2+1][mm] = e1;
        bsum += e0 + e1;
    }
    ra = am ? *(const float2*)(aptr + 16) : z2;
    rb = *(const float2*)(bptr + 16);
    __syncthreads();
    for (int s = 0; s < NS; ++s) {
        int b = s & 1;
        float2 fa = z2, fb = z2;
        if (s + 2 < NS) {
            fa = am ? *(const float2*)(aptr + (s+2)*16) : z2;
            fb = *(const float2*)(bptr + (s+2)*16);
        }
        GEMM_COMPUTE4(As[kg][b], Bs[kg][b]);
        if (s + 1 < NS) {
            int nb = b ^ 1;
            As[kg][nb][kq2][mm] = ra.x; As[kg][nb][kq2+1][mm] = ra.y;
            float e0 = fast_exp2(s2 * rb.x), e1 = fast_exp2(s2 * rb.y);
            Bs[kg][nb][kq2][mm] = e0; Bs[kg][nb][kq2+1][mm] = e1;
            bsum += e0 + e1;
        }
        __syncthreads();
        ra = fa; rb = fb;
    }
    atomicAdd(&colsum[mm], bsum);
    int r0 = ty*2, cc = tx*2;
    if (kg == 1) {
        Cmb[r0+0][cc] = a00; Cmb[r0+0][cc+1] = a01;
        Cmb[r0+1][cc] = a10; Cmb[r0+1][cc+1] = a11;
    }
    __syncthreads();
    if (tid < 32) colsum[tid] = 1.f / colsum[tid];
    __syncthreads();
    if (kg == 0) {
        float i0 = colsum[cc], i1 = colsum[cc+1];
        Tile[r0+0][cc] = (Cmb[r0+0][cc] + a00) * i0; Tile[r0+0][cc+1] = (Cmb[r0+0][cc+1] + a01) * i1;
        Tile[r0+1][cc] = (Cmb[r0+1][cc] + a10) * i0; Tile[r0+1][cc+1] = (Cmb[r0+1][cc+1] + a11) * i1;
    }
    __syncthreads();
    float su[4] = {0,0,0,0}, sq[4] = {0,0,0,0};
    if (tid < 256) {
        int tr = tid >> 3, jj = tid & 7;
        int tok = m0 + tr;
        bool act = tok < N_TOK;
        float c0 = Tile[tr][4*jj], c1 = Tile[tr][4*jj+1];
        float c2 = Tile[tr][4*jj+2], c3 = Tile[tr][4*jj+3];
        int m_kv = (n0/4 + jj) * 196 + tok;
        #pragma unroll
        for (int h = 0; h < 4; ++h) {
            float kh = c0*Wk[h] + c1*Wk[4+h] + c2*Wk[8+h] + c3*Wk[12+h];
            float vh = c0*Wv[h] + c1*Wv[4+h] + c2*Wv[8+h] + c3*Wv[12+h];
            if (act) {
                KV[h * M_KV + m_kv] = make_float2(kh, vh);
                su[h] += kh; sq[h] += kh * kh;
            }
        }
    }
    __syncthreads();
    #pragma unroll
    for (int h = 0; h < 4; ++h) {
        #pragma unroll
        for (int o = 32; o > 0; o >>= 1) {
            su[h] += __shfl_xor(su[h], o, 64);
            sq[h] += __shfl_xor(sq[h], o, 64);
        }
        if (lane == 0) { red[wid][h*2+0] = su[h]; red[wid][h*2+1] = sq[h]; }
    }
    __syncthreads();
    if (tid < 8) {
        int h = tid & 3, st = tid >> 2;
        float r = 0.f;
        #pragma unroll
        for (int w = 0; w < 8; ++w) r += red[w][h*2+st];
        kpart[st * 512 + h * 128 + bid] = r;
    }
}

// -------- K4: branch attention, full-K per block, in-block finalize ---------
// grid = 196 blocks x 1024. Wave w: head h = w>>2, K-quarter p = w&3.
#define QG 49
__global__ __launch_bounds__(1024) void k_branch(
        const float* __restrict__ emb1, const float* __restrict__ emb2,
        const float* __restrict__ emb3, const float* __restrict__ emb4,
        const float* __restrict__ Wq1, const float* __restrict__ Wq2,
        const float* __restrict__ Wq3, const float* __restrict__ Wq4,
        const float* __restrict__ g2v,
        const float2* __restrict__ KV, const float* __restrict__ kpart,
        const float* __restrict__ Wo1, const float* __restrict__ Wo2,
        const float* __restrict__ Wo3, const float* __restrict__ Wo4,
        float* __restrict__ out) {
    __shared__ float lsh[4][4][4];
    __shared__ float ash[4][4][4];
    int tid = threadIdx.x;
    int w = tid >> 6, lane = tid & 63;
    int h = w >> 2, p = w & 3;
    int bid = blockIdx.x;
    int i = bid / QG, qg = bid % QG;
    const float* emb = (i == 0) ? emb1 : (i == 1) ? emb2 : (i == 2) ? emb3 : emb4;
    const float* Wq  = (i == 0) ? Wq1 : (i == 1) ? Wq2 : (i == 2) ? Wq3 : Wq4;
    float wq0 = Wq[h], wq1 = Wq[4+h], wq2 = Wq[8+h], wq3 = Wq[12+h];
    float s = 0.f, s2 = 0.f;
    #pragma unroll
    for (int r = 0; r < 4; ++r) {
        int tt = lane + r * 64;
        if (tt < N_TOK) {
            float Q = emb[tt*4]*wq0 + emb[tt*4+1]*wq1 + emb[tt*4+2]*wq2 + emb[tt*4+3]*wq3;
            s += Q; s2 += Q * Q;
        }
    }
    float ks  = kpart[0*512 + h*128 + lane];
    float kq2 = kpart[1*512 + h*128 + lane];
    if (lane + 64 < 105) {
        ks  += kpart[0*512 + h*128 + 64 + lane];
        kq2 += kpart[1*512 + h*128 + 64 + lane];
    }
    #pragma unroll
    for (int o = 32; o > 0; o >>= 1) {
        s += __shfl_xor(s, o, 64); s2 += __shfl_xor(s2, o, 64);
        ks += __shfl_xor(ks, o, 64); kq2 += __shfl_xor(kq2, o, 64);
    }
    float Qbar = s * (1.f/196.f), Q2bar = s2 * (1.f/196.f);
    float Kbar = ks * (1.f/(float)M_KV), K2bar = kq2 * (1.f/(float)M_KV);
    float mu = Qbar * Kbar;
    float var = Q2bar * K2bar - mu * mu;
    float sc = g2v[h] * rsqrtf(var + EPSN);
    float B2[4];
    #pragma unroll
    for (int j = 0; j < 4; ++j) {
        int q = qg * 4 + j;
        float Qj = emb[q*4]*wq0 + emb[q*4+1]*wq1 + emb[q*4+2]*wq2 + emb[q*4+3]*wq3;
        B2[j] = Qj * sc * LOG2E;
    }
    const float4* kv4 = (const float4*)(KV + h * M_KV);
    const int KQ = M_KV / 8;
    int kstart = p * KQ, kendq = kstart + KQ;
    float l[4] = {0,0,0,0};
    float a[4] = {0,0,0,0};
#define PROC8(P) { \
        _Pragma("unroll") \
        for (int j = 0; j < 4; ++j) { \
            float x = fast_exp2(B2[j] * P.x); \
            l[j] += x; a[j] = fmaf(x, P.y, a[j]); \
            float y = fast_exp2(B2[j] * P.z); \
            l[j] += y; a[j] = fmaf(y, P.w, a[j]); \
        } }
    int k4 = kstart + lane;
    for (; k4 + 192 < kendq; k4 += 256) {
        float4 p0 = kv4[k4], p1 = kv4[k4+64], p2 = kv4[k4+128], p3 = kv4[k4+192];
        PROC8(p0); PROC8(p1); PROC8(p2); PROC8(p3);
    }
    for (; k4 < kendq; k4 += 64) { float4 pv = kv4[k4]; PROC8(pv); }
#undef PROC8
    #pragma unroll
    for (int j = 0; j < 4; ++j) {
        float lv = l[j], av = a[j];
        #pragma unroll
        for (int o = 32; o > 0; o >>= 1) { lv += __shfl_xor(lv, o, 64); av += __shfl_xor(av, o, 64); }
        if (lane == 0) { lsh[h][p][j] = lv; ash[h][p][j] = av; }
    }
    __syncthreads();
    if (tid < 4) {
        const float* Wo = (i == 0) ? Wo1 : (i == 1) ? Wo2 : (i == 2) ? Wo3 : Wo4;
        int j = tid;
        float c[4];
        #pragma unroll
        for (int hh = 0; hh < 4; ++hh) {
            float L = lsh[hh][0][j] + lsh[hh][1][j] + lsh[hh][2][j] + lsh[hh][3][j];
            float A = ash[hh][0][j] + ash[hh][1][j] + ash[hh][2][j] + ash[hh][3][j];
            c[hh] = A / L;
        }
        float4 o;
        o.x = c[0]*Wo[0] + c[1]*Wo[4] + c[2]*Wo[8]  + c[3]*Wo[12];
        o.y = c[0]*Wo[1] + c[1]*Wo[5] + c[2]*Wo[9]  + c[3]*Wo[13];
        o.z = c[0]*Wo[2] + c[1]*Wo[6] + c[2]*Wo[10] + c[3]*Wo[14];
        o.w = c[0]*Wo[3] + c[1]*Wo[7] + c[2]*Wo[11] + c[3]*Wo[15];
        *(float4*)(out + i * 784 + (qg * 4 + j) * 4) = o;
    }
}

extern "C" void kernel_launch(void* const* d_in, const int* in_sizes, int n_in,
                              void* d_out, int out_size, void* d_ws, size_t ws_size,
                              hipStream_t stream) {
    const float* emb1 = (const float*)d_in[0];
    const float* emb2 = (const float*)d_in[1];
    const float* emb3 = (const float*)d_in[2];
    const float* emb4 = (const float*)d_in[3];
    const float* embC = (const float*)d_in[4];
    const float* WqC  = (const float*)d_in[5];
    const float* WkC  = (const float*)d_in[6];
    const float* WvC  = (const float*)d_in[7];
    const float* Wq1  = (const float*)d_in[8];
    const float* Wq2  = (const float*)d_in[9];
    const float* Wq3  = (const float*)d_in[10];
    const float* Wq4  = (const float*)d_in[11];
    const float* Wk   = (const float*)d_in[12];
    const float* Wv   = (const float*)d_in[13];
    const float* Wo1  = (const float*)d_in[14];
    const float* Wo2  = (const float*)d_in[15];
    const float* Wo3  = (const float*)d_in[16];
    const float* Wo4  = (const float*)d_in[17];
    const float* g1   = (const float*)d_in[18];
    const float* g2   = (const float*)d_in[20];
    float* ws = (float*)d_ws;
    float* out = (float*)d_out;

    k_qkv<<<180, 512, 0, stream>>>(embC, WqC, WkC, WvC, ws);
    k_attn<<<dim3(15, 15), 512, 0, stream>>>(ws + OFF_QC, ws + OFF_KC,
                                             ws + OFF_ATTN, ws + OFF_SPART);
    k_thatkv<<<105, 512, 0, stream>>>(ws + OFF_VC, ws + OFF_ATTN, ws + OFF_SPART, g1,
                                      Wk, Wv, (float2*)(ws + OFF_KV), ws + OFF_KPART);
    k_branch<<<4 * QG, 1024, 0, stream>>>(emb1, emb2, emb3, emb4,
                                          Wq1, Wq2, Wq3, Wq4, g2,
                                          (const float2*)(ws + OFF_KV), ws + OFF_KPART,
                                          Wo1, Wo2, Wo3, Wo4, out);
}